// Round 7
// baseline (9510.339 us; speedup 1.0000x reference)
//
#include <hip/hip_runtime.h>
#include <math.h>

#define N_NODES 10000
#define IN_DIM  256
#define HID     512
#define NH      4
#define HDIM    128
#define DEG     16
#define KNN_K   15
#define QDIM    32
#define EB      64
#define EIG_PAIRS 16
#define JAC_SWEEPS 8
#define SLOPE   0.2f

typedef unsigned short u16;
typedef __attribute__((ext_vector_type(8))) short short8;
typedef __attribute__((ext_vector_type(4))) float f32x4;

__device__ __forceinline__ u16 f2bf(float x) {
  union { float f; unsigned u; } v; v.f = x;
  unsigned r = (v.u + 0x7fffu + ((v.u >> 16) & 1u)) >> 16;
  return (u16)r;
}
__device__ __forceinline__ float bf2f(u16 h) {
  union { unsigned u; float f; } v; v.u = ((unsigned)h) << 16;
  return v.f;
}

// ------------------------------------------------ fp32 GEMM (upstream of KNN)
__global__ __launch_bounds__(256) void gemm_kernel(
    const float* __restrict__ A, const float* __restrict__ B,
    const float* __restrict__ bias, float* __restrict__ C,
    int n, int k, int m, int act) {
  __shared__ float As[16][140];
  __shared__ float Bs[16][140];
  int t = threadIdx.x, tx = t & 15, ty = t >> 4;
  int r0 = blockIdx.y * 128, c0 = blockIdx.x * 128;
  float acc[8][8] = {};
  for (int k0 = 0; k0 < k; k0 += 16) {
    for (int c = t; c < 512; c += 256) {
      int row = c >> 2, kc = (c & 3) << 2;
      int gr = r0 + row;
      float4 v = make_float4(0.f, 0.f, 0.f, 0.f);
      if (gr < n) v = *(const float4*)(A + (size_t)gr * k + k0 + kc);
      As[kc][row] = v.x; As[kc + 1][row] = v.y;
      As[kc + 2][row] = v.z; As[kc + 3][row] = v.w;
    }
    for (int c = t; c < 512; c += 256) {
      int kr = c >> 5, cc = (c & 31) << 2;
      *(float4*)&Bs[kr][cc] = *(const float4*)(B + (size_t)(k0 + kr) * m + c0 + cc);
    }
    __syncthreads();
#pragma unroll
    for (int kk = 0; kk < 16; kk++) {
      float a[8], b[8];
      *(float4*)&a[0] = *(float4*)&As[kk][ty * 8];
      *(float4*)&a[4] = *(float4*)&As[kk][ty * 8 + 4];
      *(float4*)&b[0] = *(float4*)&Bs[kk][tx * 8];
      *(float4*)&b[4] = *(float4*)&Bs[kk][tx * 8 + 4];
#pragma unroll
      for (int i = 0; i < 8; i++)
#pragma unroll
        for (int j = 0; j < 8; j++) acc[i][j] += a[i] * b[j];
    }
    __syncthreads();
  }
  for (int i = 0; i < 8; i++) {
    int gr = r0 + ty * 8 + i;
    if (gr >= n) break;
    for (int j = 0; j < 8; j++) {
      int gc = c0 + tx * 8 + j;
      float v = acc[i][j] + (bias ? bias[gc] : 0.f);
      if (act == 1) v = fmaxf(v, 0.f);
      C[(size_t)gr * m + gc] = v;
    }
  }
}

// ------------------------------------------------ split-bf16 conversion
__global__ void hsplit_kernel(const float* __restrict__ h,
                              u16* __restrict__ hi, u16* __restrict__ lo) {
  int i = (blockIdx.x * 256 + threadIdx.x) * 4;
  float4 v = *(const float4*)(h + i);
  ushort4 hh, ll;
  hh.x = f2bf(v.x); ll.x = f2bf(v.x - bf2f(hh.x));
  hh.y = f2bf(v.y); ll.y = f2bf(v.y - bf2f(hh.y));
  hh.z = f2bf(v.z); ll.z = f2bf(v.z - bf2f(hh.z));
  hh.w = f2bf(v.w); ll.w = f2bf(v.w - bf2f(hh.w));
  *(ushort4*)(hi + i) = hh;
  *(ushort4*)(lo + i) = ll;
}

__global__ void wsplit_kernel(const float* __restrict__ W,
                              u16* __restrict__ thi, u16* __restrict__ tlo) {
  __shared__ float sh[32][33];
  int k0 = blockIdx.y * 32, n0 = blockIdx.x * 32;
  int t = threadIdx.x;
  for (int e = t; e < 1024; e += 256)
    sh[e >> 5][e & 31] = W[(size_t)(k0 + (e >> 5)) * 512 + n0 + (e & 31)];
  __syncthreads();
  for (int e = t; e < 1024; e += 256) {
    int nn = e >> 5, kk = e & 31;
    float a = sh[kk][nn];
    u16 h_ = f2bf(a);
    thi[(size_t)(n0 + nn) * 512 + k0 + kk] = h_;
    tlo[(size_t)(n0 + nn) * 512 + k0 + kk] = f2bf(a - bf2f(h_));
  }
}

// ------------------------------------------------ split-bf16 MFMA GEMM (layer 1)
__global__ __launch_bounds__(256) void gemm_bf16s_kernel(
    const u16* __restrict__ Ahi, const u16* __restrict__ Alo,
    const u16* __restrict__ Bthi, const u16* __restrict__ Btlo,
    const float* __restrict__ bias, float* __restrict__ C) {
  __shared__ u16 As[2][128][40];
  __shared__ u16 Bs[2][128][40];
  int t = threadIdx.x;
  int w = t >> 6, lane = t & 63;
  int wm = w >> 1, wn = w & 1;
  int m16 = lane & 15, q8 = (lane >> 4) * 8, q4 = (lane >> 4) * 4;
  int r0 = blockIdx.y * 128, n0 = blockIdx.x * 128;
  f32x4 acc[4][4] = {};
  for (int kt = 0; kt < 512; kt += 32) {
    for (int c = t; c < 512; c += 256) {
      int row = c >> 2, k8 = c & 3;
      int gr = r0 + row;
      uint4 vh = make_uint4(0, 0, 0, 0), vl = vh;
      if (gr < N_NODES) {
        vh = *(const uint4*)(Ahi + (size_t)gr * 512 + kt + k8 * 8);
        vl = *(const uint4*)(Alo + (size_t)gr * 512 + kt + k8 * 8);
      }
      *(uint4*)&As[0][row][k8 * 8] = vh;
      *(uint4*)&As[1][row][k8 * 8] = vl;
      uint4 wh = *(const uint4*)(Bthi + (size_t)(n0 + row) * 512 + kt + k8 * 8);
      uint4 wl = *(const uint4*)(Btlo + (size_t)(n0 + row) * 512 + kt + k8 * 8);
      *(uint4*)&Bs[0][row][k8 * 8] = wh;
      *(uint4*)&Bs[1][row][k8 * 8] = wl;
    }
    __syncthreads();
    short8 ah[4], al[4], bh[4], bl[4];
#pragma unroll
    for (int f = 0; f < 4; f++) {
      ah[f] = *(const short8*)&As[0][wm * 64 + f * 16 + m16][q8];
      al[f] = *(const short8*)&As[1][wm * 64 + f * 16 + m16][q8];
      bh[f] = *(const short8*)&Bs[0][wn * 64 + f * 16 + m16][q8];
      bl[f] = *(const short8*)&Bs[1][wn * 64 + f * 16 + m16][q8];
    }
#pragma unroll
    for (int fm = 0; fm < 4; fm++)
#pragma unroll
      for (int fn = 0; fn < 4; fn++) {
        acc[fm][fn] = __builtin_amdgcn_mfma_f32_16x16x32_bf16(ah[fm], bh[fn], acc[fm][fn], 0, 0, 0);
        acc[fm][fn] = __builtin_amdgcn_mfma_f32_16x16x32_bf16(ah[fm], bl[fn], acc[fm][fn], 0, 0, 0);
        acc[fm][fn] = __builtin_amdgcn_mfma_f32_16x16x32_bf16(al[fm], bh[fn], acc[fm][fn], 0, 0, 0);
      }
    __syncthreads();
  }
#pragma unroll
  for (int fm = 0; fm < 4; fm++)
#pragma unroll
    for (int fn = 0; fn < 4; fn++) {
      int gc = n0 + wn * 64 + fn * 16 + m16;
      float bv = bias ? bias[gc] : 0.f;
#pragma unroll
      for (int r = 0; r < 4; r++) {
        int gr = r0 + wm * 64 + fm * 16 + q4 + r;
        if (gr < N_NODES) C[(size_t)gr * 512 + gc] = acc[fm][fn][r] + bv;
      }
    }
}

// ---------------------------------------------------------------- eigen path
// colmean two-stage (no atomics): 40 partial blocks -> reduce
__global__ void colmean_part_kernel(const float* __restrict__ h, double* __restrict__ part) {
  int t = threadIdx.x;
  int rbeg = blockIdx.x * 250, rend = rbeg + 250;
  double s0 = 0, s1 = 0;
  for (int r = rbeg; r < rend; r++) {
    s0 += (double)h[(size_t)r * HID + t];
    s1 += (double)h[(size_t)r * HID + t + 256];
  }
  part[(size_t)blockIdx.x * 512 + t] = s0;
  part[(size_t)blockIdx.x * 512 + t + 256] = s1;
}
__global__ void colmean_reduce_kernel(const double* __restrict__ part, double* __restrict__ mu) {
  int t = blockIdx.x * 256 + threadIdx.x;
  double s = 0;
  for (int b = 0; b < 40; b++) s += part[(size_t)b * 512 + t];
  mu[t] = s;
}

// C[i][j] = sum_n (h[n][i]-mu_i)(h[n][j]-mu_j), fp64
__global__ void gram_kernel(const float* __restrict__ h, const double* __restrict__ mu,
                            double* __restrict__ C) {
  __shared__ double Ai[64][33];
  __shared__ double Aj[64][33];
  int i0 = blockIdx.y * 32, j0 = blockIdx.x * 32;
  int tid = threadIdx.x;
  int tx = tid % 16, ty = tid / 16;
  double acc[2][2] = {};
  const double invN = 1.0 / (double)N_NODES;
  for (int n0 = 0; n0 < N_NODES; n0 += 64) {
    for (int e = tid; e < 64 * 32; e += 256) {
      int rr = e / 32, cc = e % 32;
      int gn = n0 + rr;
      double vi = 0, vj = 0;
      if (gn < N_NODES) {
        vi = (double)h[(size_t)gn * HID + i0 + cc] - mu[i0 + cc] * invN;
        vj = (double)h[(size_t)gn * HID + j0 + cc] - mu[j0 + cc] * invN;
      }
      Ai[rr][cc] = vi; Aj[rr][cc] = vj;
    }
    __syncthreads();
    int nmax = min(64, N_NODES - n0);
    for (int nn = 0; nn < nmax; nn++) {
      double ai0 = Ai[nn][ty * 2], ai1 = Ai[nn][ty * 2 + 1];
      double aj0 = Aj[nn][tx * 2], aj1 = Aj[nn][tx * 2 + 1];
      acc[0][0] += ai0 * aj0; acc[0][1] += ai0 * aj1;
      acc[1][0] += ai1 * aj0; acc[1][1] += ai1 * aj1;
    }
    __syncthreads();
  }
  for (int a = 0; a < 2; a++)
    for (int b = 0; b < 2; b++)
      C[(size_t)(i0 + ty * 2 + a) * HID + j0 + tx * 2 + b] = acc[a][b];
}

// dedicated fp64 512^3 GEMM
__global__ __launch_bounds__(256) void dgemm512_kernel(
    const double* __restrict__ A, const double* __restrict__ B, double* __restrict__ C) {
  __shared__ double As[16][66];
  __shared__ double Bs[16][66];
  int t = threadIdx.x, tx = t & 15, ty = t >> 4;
  int r0 = blockIdx.y * 64, c0 = blockIdx.x * 64;
  double acc[4][4] = {};
  for (int k0 = 0; k0 < 512; k0 += 16) {
    for (int e = t; e < 1024; e += 256) {
      int row = e >> 4, kk = e & 15;
      As[kk][row] = A[(size_t)(r0 + row) * 512 + k0 + kk];
    }
    for (int e = t; e < 1024; e += 256) {
      int kk = e >> 6, col = e & 63;
      Bs[kk][col] = B[(size_t)(k0 + kk) * 512 + c0 + col];
    }
    __syncthreads();
#pragma unroll
    for (int kk = 0; kk < 16; kk++) {
      double a[4], b[4];
#pragma unroll
      for (int i = 0; i < 4; i++) { a[i] = As[kk][ty * 4 + i]; b[i] = Bs[kk][tx * 4 + i]; }
#pragma unroll
      for (int i = 0; i < 4; i++)
#pragma unroll
        for (int j = 0; j < 4; j++) acc[i][j] += a[i] * b[j];
    }
    __syncthreads();
  }
  for (int i = 0; i < 4; i++)
    for (int j = 0; j < 4; j++)
      C[(size_t)(r0 + ty * 4 + i) * 512 + c0 + tx * 4 + j] = acc[i][j];
}

__global__ void initx_kernel(double* X) {
  int i = blockIdx.x * 256 + threadIdx.x;
  if (i < HID * EB) {
    unsigned u = (unsigned)i * 2654435761u + 12345u;
    u ^= u >> 16; u *= 2246822519u; u ^= u >> 13; u *= 3266489917u; u ^= u >> 16;
    X[i] = (double)(u & 0xFFFFFF) / (double)0x1000000 - 0.5;
  }
}

// T = A^T B  for A,B [512 x 64]
__global__ void atb_kernel(const double* __restrict__ A, const double* __restrict__ B,
                           double* __restrict__ T) {
  __shared__ double part[4][64];
  int r = blockIdx.x;
  int j = threadIdx.x % 64;
  int ch = threadIdx.x / 64;
  double s = 0;
  for (int kk = ch * 128; kk < ch * 128 + 128; kk++)
    s += A[kk * EB + r] * B[kk * EB + j];
  part[ch][j] = s;
  __syncthreads();
  if (threadIdx.x < 64)
    T[r * EB + j] = part[0][j] + part[1][j] + part[2][j] + part[3][j];
}

// Y = C4 @ X (plain multiply)
__global__ __launch_bounds__(256) void ymul_kernel(
    const double* __restrict__ C4, const double* __restrict__ X,
    double* __restrict__ Y) {
  __shared__ double Xs[64][65];
  __shared__ double Cs[8][64];
  int t = threadIdx.x;
  int r0 = blockIdx.x * 8;
  int ri = t >> 5, c = t & 31;
  double acc0 = 0, acc1 = 0;
  for (int kc = 0; kc < 512; kc += 64) {
    __syncthreads();
    for (int e = t; e < 4096; e += 256)
      Xs[e >> 6][e & 63] = X[(size_t)(kc + (e >> 6)) * 64 + (e & 63)];
    for (int e = t; e < 512; e += 256)
      Cs[e >> 6][e & 63] = C4[(size_t)(r0 + (e >> 6)) * 512 + kc + (e & 63)];
    __syncthreads();
#pragma unroll 16
    for (int k = 0; k < 64; k++) {
      double a = Cs[ri][k];
      acc0 += a * Xs[k][c];
      acc1 += a * Xs[k][c + 32];
    }
  }
  Y[(size_t)(r0 + ri) * 64 + c] = acc0;
  Y[(size_t)(r0 + ri) * 64 + c + 32] = acc1;
}

// Y = C4 @ X; per-block Gpart[b] = Yslice^T Yslice
__global__ __launch_bounds__(256) void ycg_kernel(
    const double* __restrict__ C4, const double* __restrict__ X,
    double* __restrict__ Y, double* __restrict__ Gpart) {
  __shared__ double Xs[64][65];
  __shared__ double Cs[8][64];
  __shared__ double Ys[8][65];
  int t = threadIdx.x;
  int b = blockIdx.x;
  int r0 = b * 8;
  int ri = t >> 5, c = t & 31;
  double acc0 = 0, acc1 = 0;
  for (int kc = 0; kc < 512; kc += 64) {
    __syncthreads();
    for (int e = t; e < 4096; e += 256)
      Xs[e >> 6][e & 63] = X[(size_t)(kc + (e >> 6)) * 64 + (e & 63)];
    for (int e = t; e < 512; e += 256)
      Cs[e >> 6][e & 63] = C4[(size_t)(r0 + (e >> 6)) * 512 + kc + (e & 63)];
    __syncthreads();
#pragma unroll 16
    for (int k = 0; k < 64; k++) {
      double a = Cs[ri][k];
      acc0 += a * Xs[k][c];
      acc1 += a * Xs[k][c + 32];
    }
  }
  __syncthreads();
  Ys[ri][c] = acc0; Ys[ri][c + 32] = acc1;
  Y[(size_t)(r0 + ri) * 64 + c] = acc0;
  Y[(size_t)(r0 + ri) * 64 + c + 32] = acc1;
  __syncthreads();
  int i4 = (t >> 4) * 4, j4 = (t & 15) * 4;
  double g[4][4] = {};
#pragma unroll
  for (int r = 0; r < 8; r++) {
    double yi[4], yj[4];
#pragma unroll
    for (int a = 0; a < 4; a++) { yi[a] = Ys[r][i4 + a]; yj[a] = Ys[r][j4 + a]; }
#pragma unroll
    for (int a = 0; a < 4; a++)
#pragma unroll
      for (int bb = 0; bb < 4; bb++) g[a][bb] += yi[a] * yj[bb];
  }
#pragma unroll
  for (int a = 0; a < 4; a++)
#pragma unroll
    for (int bb = 0; bb < 4; bb++)
      Gpart[(size_t)b * 4096 + (i4 + a) * 64 + j4 + bb] = g[a][bb];
}

// gchol: coalesced Gpart sum; parallel right-looking Cholesky; X = Y R^-1
__global__ __launch_bounds__(256, 1) void gchol_kernel(
    const double* __restrict__ Gpart, const double* __restrict__ Y,
    double* __restrict__ X) {
  __shared__ double M[64 * 65];
  __shared__ double sc[2];
  int t = threadIdx.x;
  double ga[8], gb_[8];
#pragma unroll
  for (int c = 0; c < 8; c++) { ga[c] = 0; gb_[c] = 0; }
  const double* Gp0 = Gpart + t * 2;
  for (int b = 0; b < 64; b++) {
    const double* Gp = Gp0 + (size_t)b * 4096;
#pragma unroll
    for (int c = 0; c < 8; c++) {
      ga[c]  += Gp[c * 512];
      gb_[c] += Gp[c * 512 + 1];
    }
  }
#pragma unroll
  for (int c = 0; c < 8; c++) {
    int e = c * 512 + t * 2;
    int r = e >> 6, cl = e & 63;
    M[r * 65 + cl]     = ga[c];
    M[r * 65 + cl + 1] = gb_[c];
  }
  __syncthreads();
  if (t == 0) {
    double dm = 1e-300;
    for (int j = 0; j < 64; j++) dm = fmax(dm, M[j * 65 + j]);
    sc[0] = dm;
  }
  __syncthreads();
  double dmax = sc[0];
  int cc = t & 63, rbase = t >> 6;
  for (int kc = 0; kc < 64; kc++) {
    if (t == 0) {
      double piv = sqrt(fmax(M[kc * 65 + kc], dmax * 1e-28));
      M[kc * 65 + kc] = piv;
      sc[1] = 1.0 / piv;
    }
    __syncthreads();
    if (t > kc && t < 64) M[t * 65 + kc] *= sc[1];
    __syncthreads();
    if (cc > kc) {
      double lc = M[cc * 65 + kc];
#pragma unroll
      for (int i = 0; i < 16; i++) {
        int r = rbase + 4 * i;
        if (r > kc) M[r * 65 + cc] -= M[r * 65 + kc] * lc;
      }
    }
    __syncthreads();
  }
  int row = blockIdx.x * 256 + t;
  double x[64];
#pragma unroll
  for (int j = 0; j < 64; j++) x[j] = Y[(size_t)row * 64 + j];
#pragma unroll
  for (int j = 0; j < 64; j++) {
    double s = x[j];
#pragma unroll
    for (int i = 0; i < j; i++) s -= x[i] * M[j * 65 + i];
    x[j] = s / M[j * 65 + j];
  }
#pragma unroll
  for (int j = 0; j < 64; j++) X[(size_t)row * 64 + j] = x[j];
}

// parallel-ordered cyclic Jacobi; read-all/write-all phases
#define TD(r, c) Td[(((r) << 6)) | (((c) + (r)) & 63)]
__global__ __launch_bounds__(256) void jacobi_kernel(
    const double* __restrict__ Tin, double* __restrict__ Ucm, int* __restrict__ sel) {
  __shared__ double Td[4096];
  __shared__ double U[4096];
  __shared__ double cs[32], sn[32];
  __shared__ int pp[32], pq[32];
  int t = threadIdx.x;
  int kcol = t & 63;
  int pbase = t >> 6;
  for (int e = t; e < 4096; e += 256) {
    int r = e >> 6, c = e & 63;
    TD(r, c) = 0.5 * (Tin[r * 64 + c] + Tin[c * 64 + r]);
    U[e] = (r == c) ? 1.0 : 0.0;
  }
  __syncthreads();
  for (int sweep = 0; sweep < JAC_SWEEPS; sweep++) {
    for (int round = 0; round < 63; round++) {
      if (t < 32) {
        int a = (t == 0) ? 0 : ((t - 1 + round) % 63) + 1;
        int b = ((62 - t + round) % 63) + 1;
        int p = min(a, b), q = max(a, b);
        pp[t] = p; pq[t] = q;
        double app = TD(p, p), aqq = TD(q, q), apq = TD(p, q);
        double c_ = 1.0, s_ = 0.0;
        double scale = fabs(app) + fabs(aqq);
        if (apq != 0.0 && fabs(apq) > scale * 1e-17) {
          double tau = (aqq - app) / (2.0 * apq);
          double tt = (tau >= 0 ? 1.0 : -1.0) / (fabs(tau) + sqrt(1.0 + tau * tau));
          c_ = 1.0 / sqrt(1.0 + tt * tt);
          s_ = tt * c_;
        }
        cs[t] = c_; sn[t] = s_;
      }
      __syncthreads();
      int p8[8], q8[8];
      double c8[8], s8[8];
#pragma unroll
      for (int i = 0; i < 8; i++) {
        int pi = pbase + 4 * i;
        p8[i] = pp[pi]; q8[i] = pq[pi]; c8[i] = cs[pi]; s8[i] = sn[pi];
      }
      double tp[8], tq[8], up[8], uq[8];
#pragma unroll
      for (int i = 0; i < 8; i++) { tp[i] = TD(p8[i], kcol); tq[i] = TD(q8[i], kcol); }
#pragma unroll
      for (int i = 0; i < 8; i++) {
        TD(p8[i], kcol) = c8[i] * tp[i] - s8[i] * tq[i];
        TD(q8[i], kcol) = s8[i] * tp[i] + c8[i] * tq[i];
      }
      __syncthreads();
#pragma unroll
      for (int i = 0; i < 8; i++) {
        tp[i] = TD(kcol, p8[i]); tq[i] = TD(kcol, q8[i]);
        up[i] = U[(p8[i] << 6) | kcol]; uq[i] = U[(q8[i] << 6) | kcol];
      }
#pragma unroll
      for (int i = 0; i < 8; i++) {
        TD(kcol, p8[i]) = c8[i] * tp[i] - s8[i] * tq[i];
        TD(kcol, q8[i]) = s8[i] * tp[i] + c8[i] * tq[i];
        U[(p8[i] << 6) | kcol] = c8[i] * up[i] - s8[i] * uq[i];
        U[(q8[i] << 6) | kcol] = s8[i] * up[i] + c8[i] * uq[i];
      }
      __syncthreads();
    }
  }
  for (int e = t; e < 4096; e += 256) Ucm[e] = U[e];
  if (t == 0) {
    double vals[64]; int idx[64];
    for (int j = 0; j < 64; j++) { vals[j] = TD(j, j); idx[j] = j; }
    for (int r = 0; r < 32; r++) {
      int best = r;
      for (int j = r + 1; j < 64; j++) if (vals[j] > vals[best]) best = j;
      double tv = vals[r]; vals[r] = vals[best]; vals[best] = tv;
      int ti = idx[r]; idx[r] = idx[best]; idx[best] = ti;
      sel[r] = idx[r];
    }
  }
}

// V[512 x 32] = X[512 x 64] @ U[:, sel]
__global__ void vmat_kernel(const double* __restrict__ X, const double* __restrict__ Ucm,
                            const int* __restrict__ sel, double* __restrict__ V) {
  int gid = blockIdx.x * 256 + threadIdx.x;
  int r = gid / QDIM, c = gid % QDIM;
  int uc = sel[c];
  double s = 0;
  for (int k = 0; k < 64; k++) s += X[r * 64 + k] * Ucm[uc * 64 + k];
  V[r * QDIM + c] = s;
}

// loc = h @ V (fp64)
__global__ void loc_kernel(const float* __restrict__ h, const double* __restrict__ V,
                           double* __restrict__ loc) {
  __shared__ float hs[8][HID];
  int r0 = blockIdx.x * 8;
  int tid = threadIdx.x;
  for (int e = tid; e < 8 * HID; e += 256) {
    int rr = e / HID, c = e % HID;
    int gr = r0 + rr;
    hs[rr][c] = (gr < N_NODES) ? h[(size_t)gr * HID + c] : 0.f;
  }
  __syncthreads();
  int rr = tid / 32, q = tid % 32;
  double s = 0;
  for (int k = 0; k < HID; k++) s += (double)hs[rr][k] * V[k * QDIM + q];
  int gr = r0 + rr;
  if (gr < N_NODES) loc[(size_t)gr * QDIM + q] = s;
}

__global__ void sq_kernel(const double* __restrict__ loc, double* __restrict__ sq) {
  int n = blockIdx.x * 256 + threadIdx.x;
  if (n < N_NODES) {
    double s = 0;
    for (int q = 0; q < QDIM; q++) { double v = loc[(size_t)n * QDIM + q]; s += v * v; }
    sq[n] = s;
  }
}

__device__ __forceinline__ bool lexless(double d1, int i1, double d2, int i2) {
  return (d1 < d2) || (d1 == d2 && i1 < i2);
}

// KNN v3: 16 nodes/block, 16 lanes/node; li + lj in LDS with stride-34 padded
// layout (conflict-free, b128 q-pair reads); 4 j's per lane; low VGPR
__global__ __launch_bounds__(256) void knn_kernel(
    const double* __restrict__ loc, const double* __restrict__ sq, int* __restrict__ knn) {
  __shared__ __align__(16) double smem_d[5760];
  double* lis = smem_d;            // 16*34 = 544
  double* ljs = smem_d + 544;      // 64*34 = 2176
  double* sqj = smem_d + 2720;     // 64
  int tid = threadIdx.x;
  int i_loc = tid >> 4, lane = tid & 15;
  int i0 = blockIdx.x * 16;
  for (int e = tid; e < 512; e += 256)
    lis[(e >> 5) * 34 + (e & 31)] = loc[(size_t)(i0 + (e >> 5)) * QDIM + (e & 31)];
  __syncthreads();
  double sqi = sq[i0 + i_loc];
  double bd[15]; int bi[15];
#pragma unroll
  for (int r = 0; r < 15; r++) { bd[r] = 1e300; bi[r] = 0x7fffffff; }
  const double* lip = lis + i_loc * 34;

  for (int j0 = 0; j0 < N_NODES; j0 += 64) {
    __syncthreads();
    for (int e = tid; e < 2048; e += 256) {
      int jj = e >> 5, q = e & 31;
      int gj = j0 + jj;
      ljs[jj * 34 + q] = (gj < N_NODES) ? loc[(size_t)gj * QDIM + q] : 0.0;
    }
    if (tid < 64) sqj[tid] = (j0 + tid < N_NODES) ? sq[j0 + tid] : 1e300;
    __syncthreads();
    double dot0 = 0, dot1 = 0, dot2 = 0, dot3 = 0;
    const double* lj0 = ljs + lane * 34;
    const double* lj1 = ljs + (lane + 16) * 34;
    const double* lj2 = ljs + (lane + 32) * 34;
    const double* lj3 = ljs + (lane + 48) * 34;
#pragma unroll
    for (int q = 0; q < 32; q += 2) {
      double2 a  = *(const double2*)(lip + q);
      double2 b0 = *(const double2*)(lj0 + q);
      double2 b1 = *(const double2*)(lj1 + q);
      double2 b2 = *(const double2*)(lj2 + q);
      double2 b3 = *(const double2*)(lj3 + q);
      dot0 += a.x * b0.x + a.y * b0.y;
      dot1 += a.x * b1.x + a.y * b1.y;
      dot2 += a.x * b2.x + a.y * b2.y;
      dot3 += a.x * b3.x + a.y * b3.y;
    }
    double dots[4] = {dot0, dot1, dot2, dot3};
#pragma unroll
    for (int s = 0; s < 4; s++) {
      int gj = j0 + lane + 16 * s;
      if (gj >= N_NODES) continue;
      double dj = sqi + sqj[lane + 16 * s] - 2.0 * dots[s];
      if (lexless(dj, gj, bd[14], bi[14])) {
        bool placed = false;
#pragma unroll
        for (int r = 14; r > 0; r--) {
          if (!placed) {
            if (lexless(bd[r - 1], bi[r - 1], dj, gj)) {
              bd[r] = dj; bi[r] = gj; placed = true;
            } else {
              bd[r] = bd[r - 1]; bi[r] = bi[r - 1];
            }
          }
        }
        if (!placed) { bd[0] = dj; bi[0] = gj; }
      }
    }
  }
  __syncthreads();
  double* mdist = smem_d;
  int* midx = (int*)(smem_d + 3840);
  int base = (i_loc * 16 + lane) * 15;
  for (int r = 0; r < 15; r++) { mdist[base + r] = bd[r]; midx[base + r] = bi[r]; }
  __syncthreads();
  if (lane == 0) {
    int ptr[16];
    for (int l2 = 0; l2 < 16; l2++) ptr[l2] = 0;
    for (int r = 0; r < 15; r++) {
      double best = 1e301; int bidx = 0x7fffffff; int bl = 0;
      for (int l2 = 0; l2 < 16; l2++) {
        if (ptr[l2] < 15) {
          double dv = mdist[(i_loc * 16 + l2) * 15 + ptr[l2]];
          int iv = midx[(i_loc * 16 + l2) * 15 + ptr[l2]];
          if (lexless(dv, iv, best, bidx)) { best = dv; bidx = iv; bl = l2; }
        }
      }
      ptr[bl]++;
      knn[(size_t)(i0 + i_loc) * KNN_K + r] = bidx;
    }
  }
}

// ---------------------------------------------------------------- GAT kernels
__global__ __launch_bounds__(256) void gatv2_kernel(
    const float* __restrict__ fs, const float* __restrict__ fd,
    const int* __restrict__ src, const float* __restrict__ attn,
    float* __restrict__ out) {
  __shared__ float part1[DEG][4], part2[DEG][4];
  __shared__ float scores[DEG][NH];
  __shared__ float aw[DEG][NH];
  int v = blockIdx.x, t = threadIdx.x;
  int wave = t / 64, lane = t % 64;
  float rfd0 = fd[(size_t)v * HID + t];
  float rfd1 = fd[(size_t)v * HID + t + 256];
  float at0 = attn[t], at1 = attn[t + 256];
  float afs0[DEG], afs1[DEG];
#pragma unroll
  for (int d = 0; d < DEG; d++) {
    int u = src[(size_t)v * DEG + d];
    float f0 = fs[(size_t)u * HID + t];
    float f1 = fs[(size_t)u * HID + t + 256];
    afs0[d] = f0; afs1[d] = f1;
    float e0 = f0 + rfd0; e0 = e0 > 0.f ? e0 : SLOPE * e0;
    float e1 = f1 + rfd1; e1 = e1 > 0.f ? e1 : SLOPE * e1;
    float v0 = e0 * at0, v1 = e1 * at1;
    for (int off = 32; off; off >>= 1) {
      v0 += __shfl_down(v0, off, 64);
      v1 += __shfl_down(v1, off, 64);
    }
    if (lane == 0) { part1[d][wave] = v0; part2[d][wave] = v1; }
  }
  __syncthreads();
  if (t < DEG * NH) {
    int d = t / NH, hh = t % NH;
    float s;
    if (hh < 2) s = part1[d][hh * 2] + part1[d][hh * 2 + 1];
    else        s = part2[d][(hh - 2) * 2] + part2[d][(hh - 2) * 2 + 1];
    scores[d][hh] = s;
  }
  __syncthreads();
  if (t < NH) {
    float m = -1e30f;
    for (int d = 0; d < DEG; d++) m = fmaxf(m, scores[d][t]);
    float ss = 0.f;
    for (int d = 0; d < DEG; d++) { float e_ = expf(scores[d][t] - m); aw[d][t] = e_; ss += e_; }
    float inv = 1.f / ss;
    for (int d = 0; d < DEG; d++) aw[d][t] *= inv;
  }
  __syncthreads();
  int h0 = t / HDIM, h1 = (t + 256) / HDIM;
  float o0 = 0.f, o1 = 0.f;
#pragma unroll
  for (int d = 0; d < DEG; d++) { o0 += aw[d][h0] * afs0[d]; o1 += aw[d][h1] * afs1[d]; }
  out[(size_t)v * HID + t] = o0;
  out[(size_t)v * HID + t + 256] = o1;
}

__global__ __launch_bounds__(256) void elr_kernel(
    const float* __restrict__ f, const float* __restrict__ al, const float* __restrict__ ar,
    float* __restrict__ el, float* __restrict__ er) {
  __shared__ float pl[4][2], pr_[4][2];
  int v = blockIdx.x, t = threadIdx.x;
  int wave = t / 64, lane = t % 64;
  float f0 = f[(size_t)v * HID + t], f1 = f[(size_t)v * HID + t + 256];
  float l0 = f0 * al[t], l1 = f1 * al[t + 256];
  float r0 = f0 * ar[t], r1 = f1 * ar[t + 256];
  for (int off = 32; off; off >>= 1) {
    l0 += __shfl_down(l0, off, 64); l1 += __shfl_down(l1, off, 64);
    r0 += __shfl_down(r0, off, 64); r1 += __shfl_down(r1, off, 64);
  }
  if (lane == 0) { pl[wave][0] = l0; pl[wave][1] = l1; pr_[wave][0] = r0; pr_[wave][1] = r1; }
  __syncthreads();
  if (t < NH) {
    float ev, rv;
    if (t < 2) { ev = pl[t * 2][0] + pl[t * 2 + 1][0]; rv = pr_[t * 2][0] + pr_[t * 2 + 1][0]; }
    else { ev = pl[(t - 2) * 2][1] + pl[(t - 2) * 2 + 1][1]; rv = pr_[(t - 2) * 2][1] + pr_[(t - 2) * 2 + 1][1]; }
    el[(size_t)v * NH + t] = ev;
    er[(size_t)v * NH + t] = rv;
  }
}

__global__ __launch_bounds__(256) void gat_agg_kernel(
    const float* __restrict__ f, const int* __restrict__ knn,
    const float* __restrict__ el, const float* __restrict__ er,
    const float* __restrict__ bias, float* __restrict__ out) {
  __shared__ float aw[KNN_K][NH];
  __shared__ int us[KNN_K];
  int v = blockIdx.x, t = threadIdx.x;
  if (t < KNN_K) us[t] = knn[(size_t)v * KNN_K + t];
  __syncthreads();
  if (t < KNN_K * NH) {
    int d = t / NH, hh = t % NH;
    float s = el[(size_t)us[d] * NH + hh] + er[(size_t)v * NH + hh];
    s = s > 0.f ? s : SLOPE * s;
    aw[d][hh] = s;
  }
  __syncthreads();
  if (t < NH) {
    float m = -1e30f;
    for (int d = 0; d < KNN_K; d++) m = fmaxf(m, aw[d][t]);
    float ss = 0.f;
    for (int d = 0; d < KNN_K; d++) { float e_ = expf(aw[d][t] - m); aw[d][t] = e_; ss += e_; }
    float inv = 1.f / ss;
    for (int d = 0; d < KNN_K; d++) aw[d][t] *= inv;
  }
  __syncthreads();
  int h0 = t / HDIM, h1 = (t + 256) / HDIM;
  float o0 = bias[t], o1 = bias[t + 256];
#pragma unroll
  for (int d = 0; d < KNN_K; d++) {
    const float* fr = f + (size_t)us[d] * HID;
    o0 += aw[d][h0] * fr[t];
    o1 += aw[d][h1] * fr[t + 256];
  }
  out[(size_t)v * HID + t] = o0;
  out[(size_t)v * HID + t + 256] = o1;
}

__global__ __launch_bounds__(256) void gate_kernel(
    const float* __restrict__ h0b, const float* __restrict__ gw,
    const float* __restrict__ gb, float* __restrict__ theta) {
  __shared__ float p[4][2];
  int v = blockIdx.x, t = threadIdx.x;
  int wave = t / 64, lane = t % 64;
  float a0 = h0b[(size_t)v * HID + t], a1 = h0b[(size_t)v * HID + t + 256];
  float s0 = a0 * gw[t * 2 + 0] + a1 * gw[(t + 256) * 2 + 0];
  float s1 = a0 * gw[t * 2 + 1] + a1 * gw[(t + 256) * 2 + 1];
  for (int off = 32; off; off >>= 1) {
    s0 += __shfl_down(s0, off, 64);
    s1 += __shfl_down(s1, off, 64);
  }
  if (lane == 0) { p[wave][0] = s0; p[wave][1] = s1; }
  __syncthreads();
  if (t == 0) {
    float x0 = p[0][0] + p[1][0] + p[2][0] + p[3][0] + gb[0];
    float x1 = p[0][1] + p[1][1] + p[2][1] + p[3][1] + gb[1];
    float m = fmaxf(x0, x1);
    float e0 = expf(x0 - m), e1 = expf(x1 - m);
    float inv = 1.f / (e0 + e1);
    theta[v * 2 + 0] = e0 * inv;
    theta[v * 2 + 1] = e1 * inv;
  }
}

__global__ void combine0_kernel(const float* __restrict__ h0b, const float* __restrict__ h1b,
                                float* __restrict__ hout) {
  size_t i = (size_t)blockIdx.x * 256 + threadIdx.x;
  if (i < (size_t)N_NODES * HID) hout[i] = fmaxf(h0b[i] + h1b[i], 0.f);
}

__global__ void combine1_kernel(const float* __restrict__ h0b, const float* __restrict__ h1b,
                                const float* __restrict__ h2b, const float* __restrict__ theta,
                                float* __restrict__ out) {
  size_t i = (size_t)blockIdx.x * 256 + threadIdx.x;
  if (i < (size_t)N_NODES * HID) {
    int v = (int)(i / HID);
    float val = h0b[i] + theta[v * 2] * h1b[i] + theta[v * 2 + 1] * h2b[i];
    out[i] = fmaxf(val, 0.f);
  }
}

// ---------------------------------------------------------------- launch
extern "C" void kernel_launch(void* const* d_in, const int* in_sizes, int n_in,
                              void* d_out, int out_size, void* d_ws, size_t ws_size,
                              hipStream_t stream) {
  const float* inputs  = (const float*)d_in[0];
  const int*   src_idx = (const int*)d_in[1];
  const float* emb_w   = (const float*)d_in[2];
  const float* emb_b   = (const float*)d_in[3];
  const float* w3      = (const float*)d_in[4];
  const float* b3      = (const float*)d_in[5];
  const float* v2_wsrc = (const float*)d_in[6];
  const float* v2_bsrc = (const float*)d_in[7];
  const float* v2_wdst = (const float*)d_in[8];
  const float* v2_bdst = (const float*)d_in[9];
  const float* v2_attn = (const float*)d_in[10];
  const float* gat_w   = (const float*)d_in[11];
  const float* gat_al  = (const float*)d_in[12];
  const float* gat_ar  = (const float*)d_in[13];
  const float* gat_bias= (const float*)d_in[14];
  const float* gate_w  = (const float*)d_in[15];
  const float* gate_b  = (const float*)d_in[16];
  float* out = (float*)d_out;

  const size_t NE = (size_t)N_NODES * HID;  // 5,120,000
  float* h    = (float*)d_ws;
  float* h0b  = h + NE;
  float* h1b  = h0b + NE;
  float* h2b  = h1b + NE;
  float* fsb  = h2b + NE;
  float* fdb  = fsb + NE;
  float* theta= fdb + NE;
  float* el   = theta + 20000;
  float* er   = el + 40000;
  double* mu  = (double*)(er + 40000);
  double* C   = mu + 512;
  double* C2  = C + 262144;
  double* C4  = C2 + 262144;
  double* X   = C4 + 262144;
  double* Y   = X + 32768;
  double* G   = Y + 32768;
  double* T   = G + 4096;
  double* Ucm = T + 4096;
  double* V   = Ucm + 4096;
  double* loc = V + 16384;
  double* sq  = loc + 320000;
  int* sel    = (int*)(sq + 10000);
  int* knn    = sel + 32;
  double* Gpart = (double*)(knn + 150000 + 16);  // 64*4096 doubles = 2 MB
  double* Y2  = Gpart + 262144;                  // 512*64

  u16* Ahi  = (u16*)h2b;
  u16* Alo  = Ahi + NE;
  u16* Bthi = (u16*)C2;
  u16* Btlo = Bthi + 512 * 512;

  dim3 gemm_grid(4, (N_NODES + 127) / 128);

  // ---- embedding (fp32 exact: upstream of KNN)
  gemm_kernel<<<gemm_grid, 256, 0, stream>>>(inputs, emb_w, emb_b, h, N_NODES, IN_DIM, HID, 1);

  // ---- layer 0 (SVD/KNN/GAT/gate are dead code for l==0)
  gemm_kernel<<<gemm_grid, 256, 0, stream>>>(h, w3, b3, h0b, N_NODES, HID, HID, 0);
  gemm_kernel<<<gemm_grid, 256, 0, stream>>>(h, v2_wsrc, v2_bsrc, fsb, N_NODES, HID, HID, 0);
  gemm_kernel<<<gemm_grid, 256, 0, stream>>>(h, v2_wdst, v2_bdst, fdb, N_NODES, HID, HID, 0);
  gatv2_kernel<<<N_NODES, 256, 0, stream>>>(fsb, fdb, src_idx, v2_attn, h1b);
  combine0_kernel<<<(int)((NE + 255) / 256), 256, 0, stream>>>(h0b, h1b, h);

  // ---- layer 1: eigen-subspace of centered Gram (fp64, exact path for KNN)
  colmean_part_kernel<<<40, 256, 0, stream>>>(h, Gpart);   // Gpart as scratch (dead here)
  colmean_reduce_kernel<<<2, 256, 0, stream>>>(Gpart, mu);
  gram_kernel<<<dim3(16, 16), 256, 0, stream>>>(h, mu, C);
  dgemm512_kernel<<<dim3(8, 8), 256, 0, stream>>>(C, C, C2);
  dgemm512_kernel<<<dim3(8, 8), 256, 0, stream>>>(C2, C2, C4);
  initx_kernel<<<128, 256, 0, stream>>>(X);
  for (int it = 0; it < EIG_PAIRS; it++) {
    ymul_kernel<<<64, 256, 0, stream>>>(C4, X, Y);
    ycg_kernel<<<64, 256, 0, stream>>>(C4, Y, Y2, Gpart);
    gchol_kernel<<<2, 256, 0, stream>>>(Gpart, Y2, X);
  }
  ymul_kernel<<<64, 256, 0, stream>>>(C4, X, Y);
  atb_kernel<<<64, 256, 0, stream>>>(X, Y, T);
  jacobi_kernel<<<1, 256, 0, stream>>>(T, Ucm, sel);
  vmat_kernel<<<64, 256, 0, stream>>>(X, Ucm, sel, V);
  loc_kernel<<<1250, 256, 0, stream>>>(h, V, loc);
  sq_kernel<<<40, 256, 0, stream>>>(loc, sq);
  knn_kernel<<<625, 256, 0, stream>>>(loc, sq, knn);

  // ---- layer 1 main path (split-bf16 MFMA GEMMs: downstream of KNN only)
  const float* w3_1   = w3 + (size_t)HID * HID;
  const float* b3_1   = b3 + HID;
  const float* wsrc_1 = v2_wsrc + (size_t)HID * HID;
  const float* bsrc_1 = v2_bsrc + HID;
  const float* wdst_1 = v2_wdst + (size_t)HID * HID;
  const float* bdst_1 = v2_bdst + HID;
  const float* attn_1 = v2_attn + HID;
  const float* gatw_1 = gat_w + (size_t)HID * HID;
  const float* al_1   = gat_al + HID;
  const float* ar_1   = gat_ar + HID;
  const float* gbias_1= gat_bias + HID;
  const float* gw_1   = gate_w + (size_t)HID * 2;
  const float* gb_1   = gate_b + 2;

  hsplit_kernel<<<5000, 256, 0, stream>>>(h, Ahi, Alo);
  dim3 wsg(16, 16);
  dim3 mfma_grid(4, (N_NODES + 127) / 128);

  wsplit_kernel<<<wsg, 256, 0, stream>>>(w3_1, Bthi, Btlo);
  gemm_bf16s_kernel<<<mfma_grid, 256, 0, stream>>>(Ahi, Alo, Bthi, Btlo, b3_1, h0b);
  wsplit_kernel<<<wsg, 256, 0, stream>>>(wsrc_1, Bthi, Btlo);
  gemm_bf16s_kernel<<<mfma_grid, 256, 0, stream>>>(Ahi, Alo, Bthi, Btlo, bsrc_1, fsb);
  wsplit_kernel<<<wsg, 256, 0, stream>>>(wdst_1, Bthi, Btlo);
  gemm_bf16s_kernel<<<mfma_grid, 256, 0, stream>>>(Ahi, Alo, Bthi, Btlo, bdst_1, fdb);
  gatv2_kernel<<<N_NODES, 256, 0, stream>>>(fsb, fdb, src_idx, attn_1, h1b);
  wsplit_kernel<<<wsg, 256, 0, stream>>>(gatw_1, Bthi, Btlo);
  gemm_bf16s_kernel<<<mfma_grid, 256, 0, stream>>>(Ahi, Alo, Bthi, Btlo, (const float*)nullptr, fsb);
  elr_kernel<<<N_NODES, 256, 0, stream>>>(fsb, al_1, ar_1, el, er);
  gat_agg_kernel<<<N_NODES, 256, 0, stream>>>(fsb, knn, el, er, gbias_1, h2b);
  gate_kernel<<<N_NODES, 256, 0, stream>>>(h0b, gw_1, gb_1, theta);
  combine1_kernel<<<(int)((NE + 255) / 256), 256, 0, stream>>>(h0b, h1b, h2b, theta, out);
}

// Round 9
// 8162.331 us; speedup vs baseline: 1.1651x; 1.1651x over previous
//
#include <hip/hip_runtime.h>
#include <math.h>

#define N_NODES 10000
#define IN_DIM  256
#define HID     512
#define NH      4
#define HDIM    128
#define DEG     16
#define KNN_K   15
#define QDIM    32
#define EB      64
#define EIG_PAIRS 16
#define JAC_SWEEPS 8
#define SLOPE   0.2f

typedef unsigned short u16;
typedef __attribute__((ext_vector_type(8))) short short8;
typedef __attribute__((ext_vector_type(4))) float f32x4;

__device__ __forceinline__ u16 f2bf(float x) {
  union { float f; unsigned u; } v; v.f = x;
  unsigned r = (v.u + 0x7fffu + ((v.u >> 16) & 1u)) >> 16;
  return (u16)r;
}
__device__ __forceinline__ float bf2f(u16 h) {
  union { unsigned u; float f; } v; v.u = ((unsigned)h) << 16;
  return v.f;
}

// ------------------------------------------------ fp32 GEMM (upstream of KNN)
__global__ __launch_bounds__(256) void gemm_kernel(
    const float* __restrict__ A, const float* __restrict__ B,
    const float* __restrict__ bias, float* __restrict__ C,
    int n, int k, int m, int act) {
  __shared__ float As[16][140];
  __shared__ float Bs[16][140];
  int t = threadIdx.x, tx = t & 15, ty = t >> 4;
  int r0 = blockIdx.y * 128, c0 = blockIdx.x * 128;
  float acc[8][8] = {};
  for (int k0 = 0; k0 < k; k0 += 16) {
    for (int c = t; c < 512; c += 256) {
      int row = c >> 2, kc = (c & 3) << 2;
      int gr = r0 + row;
      float4 v = make_float4(0.f, 0.f, 0.f, 0.f);
      if (gr < n) v = *(const float4*)(A + (size_t)gr * k + k0 + kc);
      As[kc][row] = v.x; As[kc + 1][row] = v.y;
      As[kc + 2][row] = v.z; As[kc + 3][row] = v.w;
    }
    for (int c = t; c < 512; c += 256) {
      int kr = c >> 5, cc = (c & 31) << 2;
      *(float4*)&Bs[kr][cc] = *(const float4*)(B + (size_t)(k0 + kr) * m + c0 + cc);
    }
    __syncthreads();
#pragma unroll
    for (int kk = 0; kk < 16; kk++) {
      float a[8], b[8];
      *(float4*)&a[0] = *(float4*)&As[kk][ty * 8];
      *(float4*)&a[4] = *(float4*)&As[kk][ty * 8 + 4];
      *(float4*)&b[0] = *(float4*)&Bs[kk][tx * 8];
      *(float4*)&b[4] = *(float4*)&Bs[kk][tx * 8 + 4];
#pragma unroll
      for (int i = 0; i < 8; i++)
#pragma unroll
        for (int j = 0; j < 8; j++) acc[i][j] += a[i] * b[j];
    }
    __syncthreads();
  }
  for (int i = 0; i < 8; i++) {
    int gr = r0 + ty * 8 + i;
    if (gr >= n) break;
    for (int j = 0; j < 8; j++) {
      int gc = c0 + tx * 8 + j;
      float v = acc[i][j] + (bias ? bias[gc] : 0.f);
      if (act == 1) v = fmaxf(v, 0.f);
      C[(size_t)gr * m + gc] = v;
    }
  }
}

// ------------------------------------------------ split-bf16 conversion
__global__ void hsplit_kernel(const float* __restrict__ h,
                              u16* __restrict__ hi, u16* __restrict__ lo) {
  int i = (blockIdx.x * 256 + threadIdx.x) * 4;
  float4 v = *(const float4*)(h + i);
  ushort4 hh, ll;
  hh.x = f2bf(v.x); ll.x = f2bf(v.x - bf2f(hh.x));
  hh.y = f2bf(v.y); ll.y = f2bf(v.y - bf2f(hh.y));
  hh.z = f2bf(v.z); ll.z = f2bf(v.z - bf2f(hh.z));
  hh.w = f2bf(v.w); ll.w = f2bf(v.w - bf2f(hh.w));
  *(ushort4*)(hi + i) = hh;
  *(ushort4*)(lo + i) = ll;
}

__global__ void wsplit_kernel(const float* __restrict__ W,
                              u16* __restrict__ thi, u16* __restrict__ tlo) {
  __shared__ float sh[32][33];
  int k0 = blockIdx.y * 32, n0 = blockIdx.x * 32;
  int t = threadIdx.x;
  for (int e = t; e < 1024; e += 256)
    sh[e >> 5][e & 31] = W[(size_t)(k0 + (e >> 5)) * 512 + n0 + (e & 31)];
  __syncthreads();
  for (int e = t; e < 1024; e += 256) {
    int nn = e >> 5, kk = e & 31;
    float a = sh[kk][nn];
    u16 h_ = f2bf(a);
    thi[(size_t)(n0 + nn) * 512 + k0 + kk] = h_;
    tlo[(size_t)(n0 + nn) * 512 + k0 + kk] = f2bf(a - bf2f(h_));
  }
}

// ------------------------------------------------ split-bf16 MFMA GEMM (layer 1)
__global__ __launch_bounds__(256) void gemm_bf16s_kernel(
    const u16* __restrict__ Ahi, const u16* __restrict__ Alo,
    const u16* __restrict__ Bthi, const u16* __restrict__ Btlo,
    const float* __restrict__ bias, float* __restrict__ C) {
  __shared__ u16 As[2][128][40];
  __shared__ u16 Bs[2][128][40];
  int t = threadIdx.x;
  int w = t >> 6, lane = t & 63;
  int wm = w >> 1, wn = w & 1;
  int m16 = lane & 15, q8 = (lane >> 4) * 8, q4 = (lane >> 4) * 4;
  int r0 = blockIdx.y * 128, n0 = blockIdx.x * 128;
  f32x4 acc[4][4] = {};
  for (int kt = 0; kt < 512; kt += 32) {
    for (int c = t; c < 512; c += 256) {
      int row = c >> 2, k8 = c & 3;
      int gr = r0 + row;
      uint4 vh = make_uint4(0, 0, 0, 0), vl = vh;
      if (gr < N_NODES) {
        vh = *(const uint4*)(Ahi + (size_t)gr * 512 + kt + k8 * 8);
        vl = *(const uint4*)(Alo + (size_t)gr * 512 + kt + k8 * 8);
      }
      *(uint4*)&As[0][row][k8 * 8] = vh;
      *(uint4*)&As[1][row][k8 * 8] = vl;
      uint4 wh = *(const uint4*)(Bthi + (size_t)(n0 + row) * 512 + kt + k8 * 8);
      uint4 wl = *(const uint4*)(Btlo + (size_t)(n0 + row) * 512 + kt + k8 * 8);
      *(uint4*)&Bs[0][row][k8 * 8] = wh;
      *(uint4*)&Bs[1][row][k8 * 8] = wl;
    }
    __syncthreads();
    short8 ah[4], al[4], bh[4], bl[4];
#pragma unroll
    for (int f = 0; f < 4; f++) {
      ah[f] = *(const short8*)&As[0][wm * 64 + f * 16 + m16][q8];
      al[f] = *(const short8*)&As[1][wm * 64 + f * 16 + m16][q8];
      bh[f] = *(const short8*)&Bs[0][wn * 64 + f * 16 + m16][q8];
      bl[f] = *(const short8*)&Bs[1][wn * 64 + f * 16 + m16][q8];
    }
#pragma unroll
    for (int fm = 0; fm < 4; fm++)
#pragma unroll
      for (int fn = 0; fn < 4; fn++) {
        acc[fm][fn] = __builtin_amdgcn_mfma_f32_16x16x32_bf16(ah[fm], bh[fn], acc[fm][fn], 0, 0, 0);
        acc[fm][fn] = __builtin_amdgcn_mfma_f32_16x16x32_bf16(ah[fm], bl[fn], acc[fm][fn], 0, 0, 0);
        acc[fm][fn] = __builtin_amdgcn_mfma_f32_16x16x32_bf16(al[fm], bh[fn], acc[fm][fn], 0, 0, 0);
      }
    __syncthreads();
  }
#pragma unroll
  for (int fm = 0; fm < 4; fm++)
#pragma unroll
    for (int fn = 0; fn < 4; fn++) {
      int gc = n0 + wn * 64 + fn * 16 + m16;
      float bv = bias ? bias[gc] : 0.f;
#pragma unroll
      for (int r = 0; r < 4; r++) {
        int gr = r0 + wm * 64 + fm * 16 + q4 + r;
        if (gr < N_NODES) C[(size_t)gr * 512 + gc] = acc[fm][fn][r] + bv;
      }
    }
}

// ---------------------------------------------------------------- eigen path
__global__ void colmean_part_kernel(const float* __restrict__ h, double* __restrict__ part) {
  int t = threadIdx.x;
  int rbeg = blockIdx.x * 250, rend = rbeg + 250;
  double s0 = 0, s1 = 0;
  for (int r = rbeg; r < rend; r++) {
    s0 += (double)h[(size_t)r * HID + t];
    s1 += (double)h[(size_t)r * HID + t + 256];
  }
  part[(size_t)blockIdx.x * 512 + t] = s0;
  part[(size_t)blockIdx.x * 512 + t + 256] = s1;
}
__global__ void colmean_reduce_kernel(const double* __restrict__ part, double* __restrict__ mu) {
  int t = blockIdx.x * 256 + threadIdx.x;
  double s = 0;
  for (int b = 0; b < 40; b++) s += part[(size_t)b * 512 + t];
  mu[t] = s;
}

// C[i][j] = sum_n (h[n][i]-mu_i)(h[n][j]-mu_j), fp64
__global__ void gram_kernel(const float* __restrict__ h, const double* __restrict__ mu,
                            double* __restrict__ C) {
  __shared__ double Ai[64][33];
  __shared__ double Aj[64][33];
  int i0 = blockIdx.y * 32, j0 = blockIdx.x * 32;
  int tid = threadIdx.x;
  int tx = tid % 16, ty = tid / 16;
  double acc[2][2] = {};
  const double invN = 1.0 / (double)N_NODES;
  for (int n0 = 0; n0 < N_NODES; n0 += 64) {
    for (int e = tid; e < 64 * 32; e += 256) {
      int rr = e / 32, cc = e % 32;
      int gn = n0 + rr;
      double vi = 0, vj = 0;
      if (gn < N_NODES) {
        vi = (double)h[(size_t)gn * HID + i0 + cc] - mu[i0 + cc] * invN;
        vj = (double)h[(size_t)gn * HID + j0 + cc] - mu[j0 + cc] * invN;
      }
      Ai[rr][cc] = vi; Aj[rr][cc] = vj;
    }
    __syncthreads();
    int nmax = min(64, N_NODES - n0);
    for (int nn = 0; nn < nmax; nn++) {
      double ai0 = Ai[nn][ty * 2], ai1 = Ai[nn][ty * 2 + 1];
      double aj0 = Aj[nn][tx * 2], aj1 = Aj[nn][tx * 2 + 1];
      acc[0][0] += ai0 * aj0; acc[0][1] += ai0 * aj1;
      acc[1][0] += ai1 * aj0; acc[1][1] += ai1 * aj1;
    }
    __syncthreads();
  }
  for (int a = 0; a < 2; a++)
    for (int b = 0; b < 2; b++)
      C[(size_t)(i0 + ty * 2 + a) * HID + j0 + tx * 2 + b] = acc[a][b];
}

// dedicated fp64 512^3 GEMM
__global__ __launch_bounds__(256) void dgemm512_kernel(
    const double* __restrict__ A, const double* __restrict__ B, double* __restrict__ C) {
  __shared__ double As[16][66];
  __shared__ double Bs[16][66];
  int t = threadIdx.x, tx = t & 15, ty = t >> 4;
  int r0 = blockIdx.y * 64, c0 = blockIdx.x * 64;
  double acc[4][4] = {};
  for (int k0 = 0; k0 < 512; k0 += 16) {
    for (int e = t; e < 1024; e += 256) {
      int row = e >> 4, kk = e & 15;
      As[kk][row] = A[(size_t)(r0 + row) * 512 + k0 + kk];
    }
    for (int e = t; e < 1024; e += 256) {
      int kk = e >> 6, col = e & 63;
      Bs[kk][col] = B[(size_t)(k0 + kk) * 512 + c0 + col];
    }
    __syncthreads();
#pragma unroll
    for (int kk = 0; kk < 16; kk++) {
      double a[4], b[4];
#pragma unroll
      for (int i = 0; i < 4; i++) { a[i] = As[kk][ty * 4 + i]; b[i] = Bs[kk][tx * 4 + i]; }
#pragma unroll
      for (int i = 0; i < 4; i++)
#pragma unroll
        for (int j = 0; j < 4; j++) acc[i][j] += a[i] * b[j];
    }
    __syncthreads();
  }
  for (int i = 0; i < 4; i++)
    for (int j = 0; j < 4; j++)
      C[(size_t)(r0 + ty * 4 + i) * 512 + c0 + tx * 4 + j] = acc[i][j];
}

__global__ void initx_kernel(double* X) {
  int i = blockIdx.x * 256 + threadIdx.x;
  if (i < HID * EB) {
    unsigned u = (unsigned)i * 2654435761u + 12345u;
    u ^= u >> 16; u *= 2246822519u; u ^= u >> 13; u *= 3266489917u; u ^= u >> 16;
    X[i] = (double)(u & 0xFFFFFF) / (double)0x1000000 - 0.5;
  }
}

// T = A^T B  for A,B [512 x 64]
__global__ void atb_kernel(const double* __restrict__ A, const double* __restrict__ B,
                           double* __restrict__ T) {
  __shared__ double part[4][64];
  int r = blockIdx.x;
  int j = threadIdx.x % 64;
  int ch = threadIdx.x / 64;
  double s = 0;
  for (int kk = ch * 128; kk < ch * 128 + 128; kk++)
    s += A[kk * EB + r] * B[kk * EB + j];
  part[ch][j] = s;
  __syncthreads();
  if (threadIdx.x < 64)
    T[r * EB + j] = part[0][j] + part[1][j] + part[2][j] + part[3][j];
}

// Y = C4 @ X (plain multiply)
__global__ __launch_bounds__(256) void ymul_kernel(
    const double* __restrict__ C4, const double* __restrict__ X,
    double* __restrict__ Y) {
  __shared__ double Xs[64][65];
  __shared__ double Cs[8][64];
  int t = threadIdx.x;
  int r0 = blockIdx.x * 8;
  int ri = t >> 5, c = t & 31;
  double acc0 = 0, acc1 = 0;
  for (int kc = 0; kc < 512; kc += 64) {
    __syncthreads();
    for (int e = t; e < 4096; e += 256)
      Xs[e >> 6][e & 63] = X[(size_t)(kc + (e >> 6)) * 64 + (e & 63)];
    for (int e = t; e < 512; e += 256)
      Cs[e >> 6][e & 63] = C4[(size_t)(r0 + (e >> 6)) * 512 + kc + (e & 63)];
    __syncthreads();
#pragma unroll 16
    for (int k = 0; k < 64; k++) {
      double a = Cs[ri][k];
      acc0 += a * Xs[k][c];
      acc1 += a * Xs[k][c + 32];
    }
  }
  Y[(size_t)(r0 + ri) * 64 + c] = acc0;
  Y[(size_t)(r0 + ri) * 64 + c + 32] = acc1;
}

// Y = C4 @ X; per-block Gpart[b] = Yslice^T Yslice
__global__ __launch_bounds__(256) void ycg_kernel(
    const double* __restrict__ C4, const double* __restrict__ X,
    double* __restrict__ Y, double* __restrict__ Gpart) {
  __shared__ double Xs[64][65];
  __shared__ double Cs[8][64];
  __shared__ double Ys[8][65];
  int t = threadIdx.x;
  int b = blockIdx.x;
  int r0 = b * 8;
  int ri = t >> 5, c = t & 31;
  double acc0 = 0, acc1 = 0;
  for (int kc = 0; kc < 512; kc += 64) {
    __syncthreads();
    for (int e = t; e < 4096; e += 256)
      Xs[e >> 6][e & 63] = X[(size_t)(kc + (e >> 6)) * 64 + (e & 63)];
    for (int e = t; e < 512; e += 256)
      Cs[e >> 6][e & 63] = C4[(size_t)(r0 + (e >> 6)) * 512 + kc + (e & 63)];
    __syncthreads();
#pragma unroll 16
    for (int k = 0; k < 64; k++) {
      double a = Cs[ri][k];
      acc0 += a * Xs[k][c];
      acc1 += a * Xs[k][c + 32];
    }
  }
  __syncthreads();
  Ys[ri][c] = acc0; Ys[ri][c + 32] = acc1;
  Y[(size_t)(r0 + ri) * 64 + c] = acc0;
  Y[(size_t)(r0 + ri) * 64 + c + 32] = acc1;
  __syncthreads();
  int i4 = (t >> 4) * 4, j4 = (t & 15) * 4;
  double g[4][4] = {};
#pragma unroll
  for (int r = 0; r < 8; r++) {
    double yi[4], yj[4];
#pragma unroll
    for (int a = 0; a < 4; a++) { yi[a] = Ys[r][i4 + a]; yj[a] = Ys[r][j4 + a]; }
#pragma unroll
    for (int a = 0; a < 4; a++)
#pragma unroll
      for (int bb = 0; bb < 4; bb++) g[a][bb] += yi[a] * yj[bb];
  }
#pragma unroll
  for (int a = 0; a < 4; a++)
#pragma unroll
    for (int bb = 0; bb < 4; bb++)
      Gpart[(size_t)b * 4096 + (i4 + a) * 64 + j4 + bb] = g[a][bb];
}

// gchol: coalesced Gpart sum; parallel right-looking Cholesky; X = Y R^-1
__global__ __launch_bounds__(256, 1) void gchol_kernel(
    const double* __restrict__ Gpart, const double* __restrict__ Y,
    double* __restrict__ X) {
  __shared__ double M[64 * 65];
  __shared__ double sc[2];
  int t = threadIdx.x;
  double ga[8], gb_[8];
#pragma unroll
  for (int c = 0; c < 8; c++) { ga[c] = 0; gb_[c] = 0; }
  const double* Gp0 = Gpart + t * 2;
  for (int b = 0; b < 64; b++) {
    const double* Gp = Gp0 + (size_t)b * 4096;
#pragma unroll
    for (int c = 0; c < 8; c++) {
      ga[c]  += Gp[c * 512];
      gb_[c] += Gp[c * 512 + 1];
    }
  }
#pragma unroll
  for (int c = 0; c < 8; c++) {
    int e = c * 512 + t * 2;
    int r = e >> 6, cl = e & 63;
    M[r * 65 + cl]     = ga[c];
    M[r * 65 + cl + 1] = gb_[c];
  }
  __syncthreads();
  if (t == 0) {
    double dm = 1e-300;
    for (int j = 0; j < 64; j++) dm = fmax(dm, M[j * 65 + j]);
    sc[0] = dm;
  }
  __syncthreads();
  double dmax = sc[0];
  int cc = t & 63, rbase = t >> 6;
  for (int kc = 0; kc < 64; kc++) {
    if (t == 0) {
      double piv = sqrt(fmax(M[kc * 65 + kc], dmax * 1e-28));
      M[kc * 65 + kc] = piv;
      sc[1] = 1.0 / piv;
    }
    __syncthreads();
    if (t > kc && t < 64) M[t * 65 + kc] *= sc[1];
    __syncthreads();
    if (cc > kc) {
      double lc = M[cc * 65 + kc];
#pragma unroll
      for (int i = 0; i < 16; i++) {
        int r = rbase + 4 * i;
        if (r > kc) M[r * 65 + cc] -= M[r * 65 + kc] * lc;
      }
    }
    __syncthreads();
  }
  int row = blockIdx.x * 256 + t;
  double x[64];
#pragma unroll
  for (int j = 0; j < 64; j++) x[j] = Y[(size_t)row * 64 + j];
#pragma unroll
  for (int j = 0; j < 64; j++) {
    double s = x[j];
#pragma unroll
    for (int i = 0; i < j; i++) s -= x[i] * M[j * 65 + i];
    x[j] = s / M[j * 65 + j];
  }
#pragma unroll
  for (int j = 0; j < 64; j++) X[(size_t)row * 64 + j] = x[j];
}

// parallel-ordered cyclic Jacobi; read-all/write-all phases
#define TD(r, c) Td[(((r) << 6)) | (((c) + (r)) & 63)]
__global__ __launch_bounds__(256) void jacobi_kernel(
    const double* __restrict__ Tin, double* __restrict__ Ucm, int* __restrict__ sel) {
  __shared__ double Td[4096];
  __shared__ double U[4096];
  __shared__ double cs[32], sn[32];
  __shared__ int pp[32], pq[32];
  int t = threadIdx.x;
  int kcol = t & 63;
  int pbase = t >> 6;
  for (int e = t; e < 4096; e += 256) {
    int r = e >> 6, c = e & 63;
    TD(r, c) = 0.5 * (Tin[r * 64 + c] + Tin[c * 64 + r]);
    U[e] = (r == c) ? 1.0 : 0.0;
  }
  __syncthreads();
  for (int sweep = 0; sweep < JAC_SWEEPS; sweep++) {
    for (int round = 0; round < 63; round++) {
      if (t < 32) {
        int a = (t == 0) ? 0 : ((t - 1 + round) % 63) + 1;
        int b = ((62 - t + round) % 63) + 1;
        int p = min(a, b), q = max(a, b);
        pp[t] = p; pq[t] = q;
        double app = TD(p, p), aqq = TD(q, q), apq = TD(p, q);
        double c_ = 1.0, s_ = 0.0;
        double scale = fabs(app) + fabs(aqq);
        if (apq != 0.0 && fabs(apq) > scale * 1e-17) {
          double tau = (aqq - app) / (2.0 * apq);
          double tt = (tau >= 0 ? 1.0 : -1.0) / (fabs(tau) + sqrt(1.0 + tau * tau));
          c_ = 1.0 / sqrt(1.0 + tt * tt);
          s_ = tt * c_;
        }
        cs[t] = c_; sn[t] = s_;
      }
      __syncthreads();
      int p8[8], q8[8];
      double c8[8], s8[8];
#pragma unroll
      for (int i = 0; i < 8; i++) {
        int pi = pbase + 4 * i;
        p8[i] = pp[pi]; q8[i] = pq[pi]; c8[i] = cs[pi]; s8[i] = sn[pi];
      }
      double tp[8], tq[8], up[8], uq[8];
#pragma unroll
      for (int i = 0; i < 8; i++) { tp[i] = TD(p8[i], kcol); tq[i] = TD(q8[i], kcol); }
#pragma unroll
      for (int i = 0; i < 8; i++) {
        TD(p8[i], kcol) = c8[i] * tp[i] - s8[i] * tq[i];
        TD(q8[i], kcol) = s8[i] * tp[i] + c8[i] * tq[i];
      }
      __syncthreads();
#pragma unroll
      for (int i = 0; i < 8; i++) {
        tp[i] = TD(kcol, p8[i]); tq[i] = TD(kcol, q8[i]);
        up[i] = U[(p8[i] << 6) | kcol]; uq[i] = U[(q8[i] << 6) | kcol];
      }
#pragma unroll
      for (int i = 0; i < 8; i++) {
        TD(kcol, p8[i]) = c8[i] * tp[i] - s8[i] * tq[i];
        TD(kcol, q8[i]) = s8[i] * tp[i] + c8[i] * tq[i];
        U[(p8[i] << 6) | kcol] = c8[i] * up[i] - s8[i] * uq[i];
        U[(q8[i] << 6) | kcol] = s8[i] * up[i] + c8[i] * uq[i];
      }
      __syncthreads();
    }
  }
  for (int e = t; e < 4096; e += 256) Ucm[e] = U[e];
  if (t == 0) {
    double vals[64]; int idx[64];
    for (int j = 0; j < 64; j++) { vals[j] = TD(j, j); idx[j] = j; }
    for (int r = 0; r < 32; r++) {
      int best = r;
      for (int j = r + 1; j < 64; j++) if (vals[j] > vals[best]) best = j;
      double tv = vals[r]; vals[r] = vals[best]; vals[best] = tv;
      int ti = idx[r]; idx[r] = idx[best]; idx[best] = ti;
      sel[r] = idx[r];
    }
  }
}

// V[512 x 32] = X[512 x 64] @ U[:, sel]
__global__ void vmat_kernel(const double* __restrict__ X, const double* __restrict__ Ucm,
                            const int* __restrict__ sel, double* __restrict__ V) {
  int gid = blockIdx.x * 256 + threadIdx.x;
  int r = gid / QDIM, c = gid % QDIM;
  int uc = sel[c];
  double s = 0;
  for (int k = 0; k < 64; k++) s += X[r * 64 + k] * Ucm[uc * 64 + k];
  V[r * QDIM + c] = s;
}

// loc = h @ V (fp64)
__global__ void loc_kernel(const float* __restrict__ h, const double* __restrict__ V,
                           double* __restrict__ loc) {
  __shared__ float hs[8][HID];
  int r0 = blockIdx.x * 8;
  int tid = threadIdx.x;
  for (int e = tid; e < 8 * HID; e += 256) {
    int rr = e / HID, c = e % HID;
    int gr = r0 + rr;
    hs[rr][c] = (gr < N_NODES) ? h[(size_t)gr * HID + c] : 0.f;
  }
  __syncthreads();
  int rr = tid / 32, q = tid % 32;
  double s = 0;
  for (int k = 0; k < HID; k++) s += (double)hs[rr][k] * V[k * QDIM + q];
  int gr = r0 + rr;
  if (gr < N_NODES) loc[(size_t)gr * QDIM + q] = s;
}

__global__ void sq_kernel(const double* __restrict__ loc, double* __restrict__ sq) {
  int n = blockIdx.x * 256 + threadIdx.x;
  if (n < N_NODES) {
    double s = 0;
    for (int q = 0; q < QDIM; q++) { double v = loc[(size_t)n * QDIM + q]; s += v * v; }
    sq[n] = s;
  }
}

__device__ __forceinline__ bool lexless(double d1, int i1, double d2, int i2) {
  return (d1 < d2) || (d1 == d2 && i1 < i2);
}

// KNN v5: verified v3 structure (stride-34 LDS, b128 q-pair reads) +
// occupancy fix: __launch_bounds__(256,4) caps VGPR at 128 (4 waves/SIMD),
// #pragma unroll 4 limits software-pipeline live set.
__global__ __launch_bounds__(256, 4) void knn_kernel(
    const double* __restrict__ loc, const double* __restrict__ sq, int* __restrict__ knn) {
  __shared__ __align__(16) double smem_d[5760];
  double* lis = smem_d;            // 16*34 = 544
  double* ljs = smem_d + 544;      // 64*34 = 2176
  double* sqj = smem_d + 2720;     // 64
  int tid = threadIdx.x;
  int i_loc = tid >> 4, lane = tid & 15;
  int i0 = blockIdx.x * 16;
  for (int e = tid; e < 512; e += 256)
    lis[(e >> 5) * 34 + (e & 31)] = loc[(size_t)(i0 + (e >> 5)) * QDIM + (e & 31)];
  __syncthreads();
  double sqi = sq[i0 + i_loc];
  double bd[15]; int bi[15];
#pragma unroll
  for (int r = 0; r < 15; r++) { bd[r] = 1e300; bi[r] = 0x7fffffff; }
  const double* lip = lis + i_loc * 34;

  for (int j0 = 0; j0 < N_NODES; j0 += 64) {
    __syncthreads();
    for (int e = tid; e < 2048; e += 256) {
      int jj = e >> 5, q = e & 31;
      int gj = j0 + jj;
      ljs[jj * 34 + q] = (gj < N_NODES) ? loc[(size_t)gj * QDIM + q] : 0.0;
    }
    if (tid < 64) sqj[tid] = (j0 + tid < N_NODES) ? sq[j0 + tid] : 1e300;
    __syncthreads();
    double dot0 = 0, dot1 = 0, dot2 = 0, dot3 = 0;
    const double* lj0 = ljs + lane * 34;
    const double* lj1 = ljs + (lane + 16) * 34;
    const double* lj2 = ljs + (lane + 32) * 34;
    const double* lj3 = ljs + (lane + 48) * 34;
#pragma unroll 4
    for (int q = 0; q < 32; q += 2) {
      double2 a  = *(const double2*)(lip + q);
      double2 b0 = *(const double2*)(lj0 + q);
      double2 b1 = *(const double2*)(lj1 + q);
      double2 b2 = *(const double2*)(lj2 + q);
      double2 b3 = *(const double2*)(lj3 + q);
      dot0 += a.x * b0.x + a.y * b0.y;
      dot1 += a.x * b1.x + a.y * b1.y;
      dot2 += a.x * b2.x + a.y * b2.y;
      dot3 += a.x * b3.x + a.y * b3.y;
    }
    double dots[4] = {dot0, dot1, dot2, dot3};
#pragma unroll
    for (int s = 0; s < 4; s++) {
      int gj = j0 + lane + 16 * s;
      if (gj >= N_NODES) continue;
      double dj = sqi + sqj[lane + 16 * s] - 2.0 * dots[s];
      if (lexless(dj, gj, bd[14], bi[14])) {
        bool placed = false;
#pragma unroll
        for (int r = 14; r > 0; r--) {
          if (!placed) {
            if (lexless(bd[r - 1], bi[r - 1], dj, gj)) {
              bd[r] = dj; bi[r] = gj; placed = true;
            } else {
              bd[r] = bd[r - 1]; bi[r] = bi[r - 1];
            }
          }
        }
        if (!placed) { bd[0] = dj; bi[0] = gj; }
      }
    }
  }
  __syncthreads();
  double* mdist = smem_d;
  int* midx = (int*)(smem_d + 3840);
  int base = (i_loc * 16 + lane) * 15;
  for (int r = 0; r < 15; r++) { mdist[base + r] = bd[r]; midx[base + r] = bi[r]; }
  __syncthreads();
  if (lane == 0) {
    int ptr[16];
    for (int l2 = 0; l2 < 16; l2++) ptr[l2] = 0;
    for (int r = 0; r < 15; r++) {
      double best = 1e301; int bidx = 0x7fffffff; int bl = 0;
      for (int l2 = 0; l2 < 16; l2++) {
        if (ptr[l2] < 15) {
          double dv = mdist[(i_loc * 16 + l2) * 15 + ptr[l2]];
          int iv = midx[(i_loc * 16 + l2) * 15 + ptr[l2]];
          if (lexless(dv, iv, best, bidx)) { best = dv; bidx = iv; bl = l2; }
        }
      }
      ptr[bl]++;
      knn[(size_t)(i0 + i_loc) * KNN_K + r] = bidx;
    }
  }
}

// ---------------------------------------------------------------- GAT kernels
__global__ __launch_bounds__(256) void gatv2_kernel(
    const float* __restrict__ fs, const float* __restrict__ fd,
    const int* __restrict__ src, const float* __restrict__ attn,
    float* __restrict__ out) {
  __shared__ float part1[DEG][4], part2[DEG][4];
  __shared__ float scores[DEG][NH];
  __shared__ float aw[DEG][NH];
  int v = blockIdx.x, t = threadIdx.x;
  int wave = t / 64, lane = t % 64;
  float rfd0 = fd[(size_t)v * HID + t];
  float rfd1 = fd[(size_t)v * HID + t + 256];
  float at0 = attn[t], at1 = attn[t + 256];
  float afs0[DEG], afs1[DEG];
#pragma unroll
  for (int d = 0; d < DEG; d++) {
    int u = src[(size_t)v * DEG + d];
    float f0 = fs[(size_t)u * HID + t];
    float f1 = fs[(size_t)u * HID + t + 256];
    afs0[d] = f0; afs1[d] = f1;
    float e0 = f0 + rfd0; e0 = e0 > 0.f ? e0 : SLOPE * e0;
    float e1 = f1 + rfd1; e1 = e1 > 0.f ? e1 : SLOPE * e1;
    float v0 = e0 * at0, v1 = e1 * at1;
    for (int off = 32; off; off >>= 1) {
      v0 += __shfl_down(v0, off, 64);
      v1 += __shfl_down(v1, off, 64);
    }
    if (lane == 0) { part1[d][wave] = v0; part2[d][wave] = v1; }
  }
  __syncthreads();
  if (t < DEG * NH) {
    int d = t / NH, hh = t % NH;
    float s;
    if (hh < 2) s = part1[d][hh * 2] + part1[d][hh * 2 + 1];
    else        s = part2[d][(hh - 2) * 2] + part2[d][(hh - 2) * 2 + 1];
    scores[d][hh] = s;
  }
  __syncthreads();
  if (t < NH) {
    float m = -1e30f;
    for (int d = 0; d < DEG; d++) m = fmaxf(m, scores[d][t]);
    float ss = 0.f;
    for (int d = 0; d < DEG; d++) { float e_ = expf(scores[d][t] - m); aw[d][t] = e_; ss += e_; }
    float inv = 1.f / ss;
    for (int d = 0; d < DEG; d++) aw[d][t] *= inv;
  }
  __syncthreads();
  int h0 = t / HDIM, h1 = (t + 256) / HDIM;
  float o0 = 0.f, o1 = 0.f;
#pragma unroll
  for (int d = 0; d < DEG; d++) { o0 += aw[d][h0] * afs0[d]; o1 += aw[d][h1] * afs1[d]; }
  out[(size_t)v * HID + t] = o0;
  out[(size_t)v * HID + t + 256] = o1;
}

__global__ __launch_bounds__(256) void elr_kernel(
    const float* __restrict__ f, const float* __restrict__ al, const float* __restrict__ ar,
    float* __restrict__ el, float* __restrict__ er) {
  __shared__ float pl[4][2], pr_[4][2];
  int v = blockIdx.x, t = threadIdx.x;
  int wave = t / 64, lane = t % 64;
  float f0 = f[(size_t)v * HID + t], f1 = f[(size_t)v * HID + t + 256];
  float l0 = f0 * al[t], l1 = f1 * al[t + 256];
  float r0 = f0 * ar[t], r1 = f1 * ar[t + 256];
  for (int off = 32; off; off >>= 1) {
    l0 += __shfl_down(l0, off, 64); l1 += __shfl_down(l1, off, 64);
    r0 += __shfl_down(r0, off, 64); r1 += __shfl_down(r1, off, 64);
  }
  if (lane == 0) { pl[wave][0] = l0; pl[wave][1] = l1; pr_[wave][0] = r0; pr_[wave][1] = r1; }
  __syncthreads();
  if (t < NH) {
    float ev, rv;
    if (t < 2) { ev = pl[t * 2][0] + pl[t * 2 + 1][0]; rv = pr_[t * 2][0] + pr_[t * 2 + 1][0]; }
    else { ev = pl[(t - 2) * 2][1] + pl[(t - 2) * 2 + 1][1]; rv = pr_[(t - 2) * 2][1] + pr_[(t - 2) * 2 + 1][1]; }
    el[(size_t)v * NH + t] = ev;
    er[(size_t)v * NH + t] = rv;
  }
}

__global__ __launch_bounds__(256) void gat_agg_kernel(
    const float* __restrict__ f, const int* __restrict__ knn,
    const float* __restrict__ el, const float* __restrict__ er,
    const float* __restrict__ bias, float* __restrict__ out) {
  __shared__ float aw[KNN_K][NH];
  __shared__ int us[KNN_K];
  int v = blockIdx.x, t = threadIdx.x;
  if (t < KNN_K) us[t] = knn[(size_t)v * KNN_K + t];
  __syncthreads();
  if (t < KNN_K * NH) {
    int d = t / NH, hh = t % NH;
    float s = el[(size_t)us[d] * NH + hh] + er[(size_t)v * NH + hh];
    s = s > 0.f ? s : SLOPE * s;
    aw[d][hh] = s;
  }
  __syncthreads();
  if (t < NH) {
    float m = -1e30f;
    for (int d = 0; d < KNN_K; d++) m = fmaxf(m, aw[d][t]);
    float ss = 0.f;
    for (int d = 0; d < KNN_K; d++) { float e_ = expf(aw[d][t] - m); aw[d][t] = e_; ss += e_; }
    float inv = 1.f / ss;
    for (int d = 0; d < KNN_K; d++) aw[d][t] *= inv;
  }
  __syncthreads();
  int h0 = t / HDIM, h1 = (t + 256) / HDIM;
  float o0 = bias[t], o1 = bias[t + 256];
#pragma unroll
  for (int d = 0; d < KNN_K; d++) {
    const float* fr = f + (size_t)us[d] * HID;
    o0 += aw[d][h0] * fr[t];
    o1 += aw[d][h1] * fr[t + 256];
  }
  out[(size_t)v * HID + t] = o0;
  out[(size_t)v * HID + t + 256] = o1;
}

__global__ __launch_bounds__(256) void gate_kernel(
    const float* __restrict__ h0b, const float* __restrict__ gw,
    const float* __restrict__ gb, float* __restrict__ theta) {
  __shared__ float p[4][2];
  int v = blockIdx.x, t = threadIdx.x;
  int wave = t / 64, lane = t % 64;
  float a0 = h0b[(size_t)v * HID + t], a1 = h0b[(size_t)v * HID + t + 256];
  float s0 = a0 * gw[t * 2 + 0] + a1 * gw[(t + 256) * 2 + 0];
  float s1 = a0 * gw[t * 2 + 1] + a1 * gw[(t + 256) * 2 + 1];
  for (int off = 32; off; off >>= 1) {
    s0 += __shfl_down(s0, off, 64);
    s1 += __shfl_down(s1, off, 64);
  }
  if (lane == 0) { p[wave][0] = s0; p[wave][1] = s1; }
  __syncthreads();
  if (t == 0) {
    float x0 = p[0][0] + p[1][0] + p[2][0] + p[3][0] + gb[0];
    float x1 = p[0][1] + p[1][1] + p[2][1] + p[3][1] + gb[1];
    float m = fmaxf(x0, x1);
    float e0 = expf(x0 - m), e1 = expf(x1 - m);
    float inv = 1.f / (e0 + e1);
    theta[v * 2 + 0] = e0 * inv;
    theta[v * 2 + 1] = e1 * inv;
  }
}

__global__ void combine0_kernel(const float* __restrict__ h0b, const float* __restrict__ h1b,
                                float* __restrict__ hout) {
  size_t i = (size_t)blockIdx.x * 256 + threadIdx.x;
  if (i < (size_t)N_NODES * HID) hout[i] = fmaxf(h0b[i] + h1b[i], 0.f);
}

__global__ void combine1_kernel(const float* __restrict__ h0b, const float* __restrict__ h1b,
                                const float* __restrict__ h2b, const float* __restrict__ theta,
                                float* __restrict__ out) {
  size_t i = (size_t)blockIdx.x * 256 + threadIdx.x;
  if (i < (size_t)N_NODES * HID) {
    int v = (int)(i / HID);
    float val = h0b[i] + theta[v * 2] * h1b[i] + theta[v * 2 + 1] * h2b[i];
    out[i] = fmaxf(val, 0.f);
  }
}

// ---------------------------------------------------------------- launch
extern "C" void kernel_launch(void* const* d_in, const int* in_sizes, int n_in,
                              void* d_out, int out_size, void* d_ws, size_t ws_size,
                              hipStream_t stream) {
  const float* inputs  = (const float*)d_in[0];
  const int*   src_idx = (const int*)d_in[1];
  const float* emb_w   = (const float*)d_in[2];
  const float* emb_b   = (const float*)d_in[3];
  const float* w3      = (const float*)d_in[4];
  const float* b3      = (const float*)d_in[5];
  const float* v2_wsrc = (const float*)d_in[6];
  const float* v2_bsrc = (const float*)d_in[7];
  const float* v2_wdst = (const float*)d_in[8];
  const float* v2_bdst = (const float*)d_in[9];
  const float* v2_attn = (const float*)d_in[10];
  const float* gat_w   = (const float*)d_in[11];
  const float* gat_al  = (const float*)d_in[12];
  const float* gat_ar  = (const float*)d_in[13];
  const float* gat_bias= (const float*)d_in[14];
  const float* gate_w  = (const float*)d_in[15];
  const float* gate_b  = (const float*)d_in[16];
  float* out = (float*)d_out;

  const size_t NE = (size_t)N_NODES * HID;  // 5,120,000
  float* h    = (float*)d_ws;
  float* h0b  = h + NE;
  float* h1b  = h0b + NE;
  float* h2b  = h1b + NE;
  float* fsb  = h2b + NE;
  float* fdb  = fsb + NE;
  float* theta= fdb + NE;
  float* el   = theta + 20000;
  float* er   = el + 40000;
  double* mu  = (double*)(er + 40000);
  double* C   = mu + 512;
  double* C2  = C + 262144;
  double* C4  = C2 + 262144;
  double* X   = C4 + 262144;
  double* Y   = X + 32768;
  double* G   = Y + 32768;
  double* T   = G + 4096;
  double* Ucm = T + 4096;
  double* V   = Ucm + 4096;
  double* loc = V + 16384;
  double* sq  = loc + 320000;
  int* sel    = (int*)(sq + 10000);
  int* knn    = sel + 32;
  double* Gpart = (double*)(knn + 150000 + 16);  // 64*4096 doubles = 2 MB
  double* Y2  = Gpart + 262144;                  // 512*64

  u16* Ahi  = (u16*)h2b;
  u16* Alo  = Ahi + NE;
  u16* Bthi = (u16*)C2;
  u16* Btlo = Bthi + 512 * 512;

  dim3 gemm_grid(4, (N_NODES + 127) / 128);

  // ---- embedding (fp32 exact: upstream of KNN)
  gemm_kernel<<<gemm_grid, 256, 0, stream>>>(inputs, emb_w, emb_b, h, N_NODES, IN_DIM, HID, 1);

  // ---- layer 0 (SVD/KNN/GAT/gate are dead code for l==0)
  gemm_kernel<<<gemm_grid, 256, 0, stream>>>(h, w3, b3, h0b, N_NODES, HID, HID, 0);
  gemm_kernel<<<gemm_grid, 256, 0, stream>>>(h, v2_wsrc, v2_bsrc, fsb, N_NODES, HID, HID, 0);
  gemm_kernel<<<gemm_grid, 256, 0, stream>>>(h, v2_wdst, v2_bdst, fdb, N_NODES, HID, HID, 0);
  gatv2_kernel<<<N_NODES, 256, 0, stream>>>(fsb, fdb, src_idx, v2_attn, h1b);
  combine0_kernel<<<(int)((NE + 255) / 256), 256, 0, stream>>>(h0b, h1b, h);

  // ---- layer 1: eigen-subspace of centered Gram (fp64, exact path for KNN)
  colmean_part_kernel<<<40, 256, 0, stream>>>(h, Gpart);   // Gpart as scratch (dead here)
  colmean_reduce_kernel<<<2, 256, 0, stream>>>(Gpart, mu);
  gram_kernel<<<dim3(16, 16), 256, 0, stream>>>(h, mu, C);
  dgemm512_kernel<<<dim3(8, 8), 256, 0, stream>>>(C, C, C2);
  dgemm512_kernel<<<dim3(8, 8), 256, 0, stream>>>(C2, C2, C4);
  initx_kernel<<<128, 256, 0, stream>>>(X);
  for (int it = 0; it < EIG_PAIRS; it++) {
    ymul_kernel<<<64, 256, 0, stream>>>(C4, X, Y);
    ycg_kernel<<<64, 256, 0, stream>>>(C4, Y, Y2, Gpart);
    gchol_kernel<<<2, 256, 0, stream>>>(Gpart, Y2, X);
  }
  ymul_kernel<<<64, 256, 0, stream>>>(C4, X, Y);
  atb_kernel<<<64, 256, 0, stream>>>(X, Y, T);
  jacobi_kernel<<<1, 256, 0, stream>>>(T, Ucm, sel);
  vmat_kernel<<<64, 256, 0, stream>>>(X, Ucm, sel, V);
  loc_kernel<<<1250, 256, 0, stream>>>(h, V, loc);
  sq_kernel<<<40, 256, 0, stream>>>(loc, sq);
  knn_kernel<<<625, 256, 0, stream>>>(loc, sq, knn);

  // ---- layer 1 main path (split-bf16 MFMA GEMMs: downstream of KNN only)
  const float* w3_1   = w3 + (size_t)HID * HID;
  const float* b3_1   = b3 + HID;
  const float* wsrc_1 = v2_wsrc + (size_t)HID * HID;
  const float* bsrc_1 = v2_bsrc + HID;
  const float* wdst_1 = v2_wdst + (size_t)HID * HID;
  const float* bdst_1 = v2_bdst + HID;
  const float* attn_1 = v2_attn + HID;
  const float* gatw_1 = gat_w + (size_t)HID * HID;
  const float* al_1   = gat_al + HID;
  const float* ar_1   = gat_ar + HID;
  const float* gbias_1= gat_bias + HID;
  const float* gw_1   = gate_w + (size_t)HID * 2;
  const float* gb_1   = gate_b + 2;

  hsplit_kernel<<<5000, 256, 0, stream>>>(h, Ahi, Alo);
  dim3 wsg(16, 16);
  dim3 mfma_grid(4, (N_NODES + 127) / 128);

  wsplit_kernel<<<wsg, 256, 0, stream>>>(w3_1, Bthi, Btlo);
  gemm_bf16s_kernel<<<mfma_grid, 256, 0, stream>>>(Ahi, Alo, Bthi, Btlo, b3_1, h0b);
  wsplit_kernel<<<wsg, 256, 0, stream>>>(wsrc_1, Bthi, Btlo);
  gemm_bf16s_kernel<<<mfma_grid, 256, 0, stream>>>(Ahi, Alo, Bthi, Btlo, bsrc_1, fsb);
  wsplit_kernel<<<wsg, 256, 0, stream>>>(wdst_1, Bthi, Btlo);
  gemm_bf16s_kernel<<<mfma_grid, 256, 0, stream>>>(Ahi, Alo, Bthi, Btlo, bdst_1, fdb);
  gatv2_kernel<<<N_NODES, 256, 0, stream>>>(fsb, fdb, src_idx, attn_1, h1b);
  wsplit_kernel<<<wsg, 256, 0, stream>>>(gatw_1, Bthi, Btlo);
  gemm_bf16s_kernel<<<mfma_grid, 256, 0, stream>>>(Ahi, Alo, Bthi, Btlo, (const float*)nullptr, fsb);
  elr_kernel<<<N_NODES, 256, 0, stream>>>(fsb, al_1, ar_1, el, er);
  gat_agg_kernel<<<N_NODES, 256, 0, stream>>>(fsb, knn, el, er, gbias_1, h2b);
  gate_kernel<<<N_NODES, 256, 0, stream>>>(h0b, gw_1, gb_1, theta);
  combine1_kernel<<<(int)((NE + 255) / 256), 256, 0, stream>>>(h0b, h1b, h2b, theta, out);
}